// Round 11
// baseline (114.210 us; speedup 1.0000x reference)
//
#include <hip/hip_runtime.h>

// YOLO-style loss: pred/target (16384, 7, 7, 14) fp32 -> scalar fp32.
// N = 14 channels: [0..4] box0 (x,y,w,h,conf), [5..9] box1, [10..13] classes.
//
// Round-11: latency-hiding via PERSISTENT PIPELINED TILES (R10 counters:
// 49 us @ 11% HBM, 15% VALU, 11.6% occ => latency-bound, waves starve).
// One wave per block, NT=4 tiles x 64 pairs, double-buffered 2x14 KB LDS.
// Steady state per iteration: vmcnt(14) [only next tile in flight] ->
// ds_read tile i -> lgkmcnt(0) fence -> issue DMA for tile i+2 into freed
// buffer -> register-only compute. A wave pays HBM latency once (prologue),
// then compute (~500ns/tile) hides the next tile's flight time.

#define NPAIRS (16384 * 7 * 7 / 2)   // 401408
#define TPB 64
#define PPW 64                        // pairs per tile
#define NT 4                          // tiles per block
#define TSLOTS (PPW * 7)              // 448 float4 slots per tensor per tile
#define NBLOCKS (NPAIRS / (PPW * NT)) // 1568, exact

typedef __attribute__((address_space(3))) void lds_void;
typedef const __attribute__((address_space(1))) void glb_void;

__device__ __forceinline__ float cell_loss(const float* __restrict__ p,
                                           const float* __restrict__ t) {
    const float conf_t = t[4];
    const float coord = (conf_t > 0.0f) ? 1.0f : 0.0f;

    // target box 0
    const float tx = t[0] / 7.0f;
    const float ty = t[1] / 7.0f;
    const float tw = t[2];
    const float th = t[3];
    const float tlx = tx - 0.5f * tw, tly = ty - 0.5f * th;
    const float trx = tx + 0.5f * tw, trY = ty + 0.5f * th;
    const float area_t = (trx - tlx) * (trY - tly);

    float iou0, iou1;
    {
        const float px = p[0] / 7.0f, py = p[1] / 7.0f;
        const float pw = p[2], ph = p[3];
        const float plx = px - 0.5f * pw, ply = py - 0.5f * ph;
        const float prx = px + 0.5f * pw, prY = py + 0.5f * ph;
        const float ltx = fmaxf(plx, tlx), lty = fmaxf(ply, tly);
        const float rbx = fminf(prx, trx), rby = fminf(prY, trY);
        const float wx = fmaxf(rbx - ltx, 0.0f), wy = fmaxf(rby - lty, 0.0f);
        const float inter = wx * wy;
        const float area_p = (prx - plx) * (prY - ply);
        iou0 = inter / (area_p + area_t - inter);
    }
    {
        const float px = p[5] / 7.0f, py = p[6] / 7.0f;
        const float pw = p[7], ph = p[8];
        const float plx = px - 0.5f * pw, ply = py - 0.5f * ph;
        const float prx = px + 0.5f * pw, prY = py + 0.5f * ph;
        const float ltx = fmaxf(plx, tlx), lty = fmaxf(ply, tly);
        const float rbx = fminf(prx, trx), rby = fminf(prY, trY);
        const float wx = fmaxf(rbx - ltx, 0.0f), wy = fmaxf(rby - lty, 0.0f);
        const float inter = wx * wy;
        const float area_p = (prx - plx) * (prY - ply);
        iou1 = inter / (area_p + area_t - inter);
    }

    // jnp.argmax: first max wins -> box1 only if strictly greater.
    const bool sel1 = (iou1 > iou0);
    const float max_iou = fmaxf(iou0, iou1);

    // Branchless responsible-box select with STATIC indexing (no scratch).
    const float rp0 = sel1 ? p[5] : p[0];
    const float rp1 = sel1 ? p[6] : p[1];
    const float rp2 = sel1 ? p[7] : p[2];
    const float rp3 = sel1 ? p[8] : p[3];
    const float rp4 = sel1 ? p[9] : p[4];
    const float rt0 = sel1 ? t[5] : t[0];
    const float rt1 = sel1 ? t[6] : t[1];
    const float rt2 = sel1 ? t[7] : t[2];
    const float rt3 = sel1 ? t[8] : t[3];

    const float dx = rp0 - rt0;
    const float dy = rp1 - rt1;
    const float l_xy = dx * dx + dy * dy;

    const float sw = sqrtf(rp2) - sqrtf(rt2);
    const float sh = sqrtf(rp3) - sqrtf(rt3);
    const float l_wh = sw * sw + sh * sh;

    const float dobj = rp4 - max_iou;
    const float l_obj = dobj * dobj;

    float l_cls = 0.0f;
#pragma unroll
    for (int c = 10; c < 14; ++c) {
        const float pc = p[c];
        const float tc = t[c];
        l_cls += -(tc * logf(pc) + (1.0f - tc) * logf(1.0f - pc));
    }

    // df loss (unmasked)
    const float q = conf_t;
    const float pp = p[4];
    const float alpha = (1.0f - q) / (1.0f - pp);
    const float l_df = alpha * (pp - q) * logf(pp) + (q - pp) * logf(1.0f - pp);

    return coord * (l_xy + l_wh + l_obj + l_cls) + l_df;
}

__global__ __launch_bounds__(TPB) void yolo_loss_kernel(
    const float* __restrict__ pred, const float* __restrict__ tgt,
    float* __restrict__ partials) {
    __shared__ float4 sp[2][TSLOTS];   // 2 x 7 KB
    __shared__ float4 st[2][TSLOTS];   // 2 x 7 KB  (28 KB total, 5 blocks/CU)

    const int lane = threadIdx.x;      // one wave per block

    const long base4 = (long)blockIdx.x * (NT * TSLOTS);  // float4 units
    const float4* __restrict__ gp = reinterpret_cast<const float4*>(pred) + base4;
    const float4* __restrict__ gt = reinterpret_cast<const float4*>(tgt) + base4;

    // issue one tile's 14 DMA loads (each 64 consecutive float4 = 1 KB).
#define ISSUE_TILE(buf, tile)                                                 \
    {                                                                         \
        _Pragma("unroll") for (int it = 0; it < 7; ++it) {                    \
            const int gs = (tile) * TSLOTS + it * 64;                         \
            const int ds = it * 64;                                           \
            __builtin_amdgcn_global_load_lds((glb_void*)(gp + gs + lane),     \
                                             (lds_void*)(&sp[buf][ds]), 16,   \
                                             0, 0);                           \
            __builtin_amdgcn_global_load_lds((glb_void*)(gt + gs + lane),     \
                                             (lds_void*)(&st[buf][ds]), 16,   \
                                             0, 0);                           \
        }                                                                     \
    }

    ISSUE_TILE(0, 0)
    ISSUE_TILE(1, 1)

    float v = 0.0f;

#pragma unroll
    for (int i = 0; i < NT; ++i) {
        const int buf = i & 1;
        // Tile i done when only the next tile's 14 loads remain in flight.
        if (i < NT - 1) {
            asm volatile("s_waitcnt vmcnt(14)" ::: "memory");
        } else {
            asm volatile("s_waitcnt vmcnt(0)" ::: "memory");
        }

        float lp[28], lt[28];
#pragma unroll
        for (int j = 0; j < 7; ++j) {
            const int s = 7 * lane + j;   // gcd(7,8)=1: bank-group clean
            reinterpret_cast<float4*>(lp)[j] = sp[buf][s];
            reinterpret_cast<float4*>(lt)[j] = st[buf][s];
        }
        // Drain ds_reads BEFORE reusing this buffer for tile i+2 (compiler
        // fence via memory clobber; DMA writes land only after issue below).
        asm volatile("s_waitcnt lgkmcnt(0)" ::: "memory");

        if (i + 2 < NT) ISSUE_TILE(buf, i + 2)

        v += cell_loss(lp, lt) + cell_loss(lp + 14, lt + 14);
    }
#undef ISSUE_TILE

    // wave-64 reduce, then one plain store per block (no atomics).
#pragma unroll
    for (int off = 32; off > 0; off >>= 1) v += __shfl_down(v, off, 64);
    if (lane == 0) partials[blockIdx.x] = v;
}

__global__ __launch_bounds__(1024) void reduce_kernel(
    const float4* __restrict__ partials4, float* __restrict__ out) {
    // 1568 partials = 392 float4, one per thread (threads >= 392 idle).
    const int tid = threadIdx.x;
    float v = 0.0f;
    if (tid < NBLOCKS / 4) {
        const float4 x = partials4[tid];
        v = (x.x + x.y) + (x.z + x.w);
    }
#pragma unroll
    for (int off = 32; off > 0; off >>= 1) v += __shfl_down(v, off, 64);
    __shared__ float s[16];
    if ((tid & 63) == 0) s[tid >> 6] = v;
    __syncthreads();
    if (tid == 0) {
        float r = 0.0f;
#pragma unroll
        for (int i = 0; i < 16; ++i) r += s[i];
        out[0] = r;
    }
}

extern "C" void kernel_launch(void* const* d_in, const int* in_sizes, int n_in,
                              void* d_out, int out_size, void* d_ws, size_t ws_size,
                              hipStream_t stream) {
    const float* pred = (const float*)d_in[0];
    const float* tgt  = (const float*)d_in[1];
    float* out = (float*)d_out;
    float* partials = (float*)d_ws;   // 1568 * 4 B of scratch

    yolo_loss_kernel<<<NBLOCKS, TPB, 0, stream>>>(pred, tgt, partials);
    reduce_kernel<<<1, 1024, 0, stream>>>(
        reinterpret_cast<const float4*>(partials), out);
}